// Round 5
// baseline (67.128 us; speedup 1.0000x reference)
//
#include <hip/hip_runtime.h>

// KaolinRenderer: coverage-mask rasterizer.
// Output = repeat(mask[B,H,W], 3) — the reference z-buffer is dead code.
//
// BIT-EXACTNESS IS CRITICAL: mask is binary, threshold 2e-2. Faces with
// w-clamped vertices (|ndc| ~1e8) have catastrophically-cancelling edge
// functions whose sign is rounding-determined. We mirror the numpy reference's
// float32 op order exactly and disable FMA contraction. Skipping faces once
// `covered` is true is safe (sticky OR); changing per-face arithmetic is not.
//
// R5: single fused kernel. Each block (16x16 tile) transforms+culls all 4096
// faces of its batch in 4 chunks of 1024 (bit-identical recomputation per
// block: deterministic IEEE f32, contract off => same NDC bits everywhere).
// Conservative half-plane interval cull at tile granularity (R4-validated
// err bound, ~16x margin); survivors' exact-test records appended to LDS via
// atomicAdd (append order irrelevant: coverage is a commutative OR). Waves
// test survivors from LDS broadcast reads with __all(covered) early break;
// block-wide __syncthreads_and early exit skips whole remaining chunks —
// including their cull work. No workspace traffic, one dispatch total.

#pragma clang fp contract(off)

#define HW      256
#define BATCH   2
#define VCOUNT  4096
#define FCOUNT  4096
#define CHUNK   1024
#define CULL_EPS 1.52587890625e-05f   // 2^-16

__global__ __launch_bounds__(256)
void fused_raster_kernel(const float* __restrict__ verts,
                         const int* __restrict__ faces,
                         const float* __restrict__ R,
                         const float* __restrict__ T,
                         float* __restrict__ out)
{
#pragma clang fp contract(off)
    // Survivor exact-test records, 3 float4 each:
    //  [0]=(x0,y0,x1,y1) [1]=(x2,y2,d01x,d01y) [2]=(d12x,d12y,d20x,d20y)
    __shared__ float4 slist[CHUNK * 3];   // 48 KiB (cap == chunk size)
    __shared__ int scount;

    int b    = blockIdx.y;
    int tile = blockIdx.x;                       // 16x16 tiles over 256x256
    int tid  = threadIdx.x;
    int tx = (tile & 15) << 4;
    int ty = (tile >> 4) << 4;
    int px_i = tx + (tid & 15);
    int py_i = ty + (tid >> 4);

    // Same formula as reference: ((i + 0.5)/W)*2 - 1
    float px = (((float)px_i + 0.5f) / 256.0f) * 2.0f - 1.0f;
    float py = (((float)py_i + 0.5f) / 256.0f) * 2.0f - 1.0f;
    // Tile rect bounds (pixel formula is monotone in index).
    float pxlo = (((float)tx        + 0.5f) / 256.0f) * 2.0f - 1.0f;
    float pxhi = (((float)(tx + 15) + 0.5f) / 256.0f) * 2.0f - 1.0f;
    float pylo = (((float)ty        + 0.5f) / 256.0f) * 2.0f - 1.0f;
    float pyhi = (((float)(ty + 15) + 0.5f) / 256.0f) * 2.0f - 1.0f;

    // VP rows 0 (x), 1 (y), 3 (w), exactly as the reference builds them.
    const float fproj = 1.7320508075688772f;   // 1/tan(30deg), f64->f32 like numpy
    const float* Rb = R + b * 9;
    const float* Tb = T + b * 3;
    float t0 = -((Rb[0*3+0]*Tb[0] + Rb[1*3+0]*Tb[1]) + Rb[2*3+0]*Tb[2]);
    float t1 = -((Rb[0*3+1]*Tb[0] + Rb[1*3+1]*Tb[1]) + Rb[2*3+1]*Tb[2]);
    float t2 = -((Rb[0*3+2]*Tb[0] + Rb[1*3+2]*Tb[1]) + Rb[2*3+2]*Tb[2]);
    float VP00 = fproj * Rb[0*3+0], VP01 = fproj * Rb[1*3+0],
          VP02 = fproj * Rb[2*3+0], VP03 = fproj * t0;
    float VP10 = fproj * Rb[0*3+1], VP11 = fproj * Rb[1*3+1],
          VP12 = fproj * Rb[2*3+1], VP13 = fproj * t1;
    float VP30 = -Rb[0*3+2], VP31 = -Rb[1*3+2],
          VP32 = -Rb[2*3+2], VP33 = -t2;

    const float* vb = verts + (size_t)b * VCOUNT * 3;
    const int*   fb = faces + (size_t)b * FCOUNT * 3;

    bool covered = false;

    for (int c0 = 0; c0 < FCOUNT; c0 += CHUNK) {
        // Block-wide early exit; also the barrier guarding slist reuse.
        if (__syncthreads_and((int)covered)) break;
        if (tid == 0) scount = 0;
        __syncthreads();

        // Phase 1: cull this chunk (4 faces per thread), append survivors.
        for (int r = 0; r < CHUNK / 256; ++r) {
            int fi = c0 + r * 256 + tid;
            const int* fp = fb + (size_t)fi * 3;
            int vi[3] = { fp[0], fp[1], fp[2] };
            float xs[3], ys[3];
#pragma unroll
            for (int j = 0; j < 3; ++j) {
                const float* vv = vb + (size_t)vi[j] * 3;
                float vx = vv[0], vy = vv[1], vz = vv[2];
                // Identical op sequence to the reference einsum (sequential
                // adds), contract off => bit-identical NDC on every block.
                float cx = ((vx*VP00 + vy*VP01) + vz*VP02) + VP03;
                float cy = ((vx*VP10 + vy*VP11) + vz*VP12) + VP13;
                float cw = ((vx*VP30 + vy*VP31) + vz*VP32) + VP33;
                float w = fmaxf(cw, 1e-8f);
                xs[j] = cx / w;
                ys[j] = cy / w;
            }
            float d01x = xs[1] - xs[0], d01y = ys[1] - ys[0];
            float d12x = xs[2] - xs[1], d12y = ys[2] - ys[1];
            float d20x = xs[0] - xs[2], d20y = ys[0] - ys[2];

            // Conservative cull: e(p) ~= A*py + B*px + C; face skippable iff
            // some edge certifies e<0 on the whole rect AND some edge
            // certifies e>0 (kills both sign branches of `inside`).
            bool killneg = false, killpos = false;
            {
                float A[3] = { d01x, d12x, d20x };
                float B[3] = { -d01y, -d12y, -d20y };
                float xa[3] = { xs[0], xs[1], xs[2] };
                float ya[3] = { ys[0], ys[1], ys[2] };
#pragma unroll
                for (int e = 0; e < 3; ++e) {
                    float C = (-B[e]) * xa[e] - A[e] * ya[e];
                    float err = CULL_EPS * (fabsf(A[e]) * (1.0f + fabsf(ya[e]))
                                          + fabsf(B[e]) * (1.0f + fabsf(xa[e])));
                    float yh = (A[e] > 0.0f) ? pyhi : pylo;
                    float yl = (A[e] > 0.0f) ? pylo : pyhi;
                    float xh = (B[e] > 0.0f) ? pxhi : pxlo;
                    float xl = (B[e] > 0.0f) ? pxlo : pxhi;
                    float hi = A[e] * yh + B[e] * xh + C;
                    float lo = A[e] * yl + B[e] * xl + C;
                    killneg = killneg || (hi < -err);
                    killpos = killpos || (lo >  err);
                }
            }
            if (!(killneg && killpos)) {
                int idx = atomicAdd(&scount, 1);   // idx < CHUNK always
                slist[idx*3 + 0] = make_float4(xs[0], ys[0], xs[1], ys[1]);
                slist[idx*3 + 1] = make_float4(xs[2], ys[2], d01x, d01y);
                slist[idx*3 + 2] = make_float4(d12x, d12y, d20x, d20y);
            }
        }
        __syncthreads();

        // Phase 2: exact test of survivors (LDS broadcast reads, conflict-
        // free); per-wave break every 8 faces once the strip is covered.
        int n = scount;
        for (int f8 = 0; f8 < n; f8 += 8) {
            if (__all((int)covered)) break;
            int fe = (f8 + 8 < n) ? f8 + 8 : n;
            for (int f = f8; f < fe; ++f) {
                float4 a = slist[f*3 + 0];
                float4 c = slist[f*3 + 1];
                float4 d = slist[f*3 + 2];
                // e = (x1-x0)*(py-y0) - (y1-y0)*(px-x0): mul,mul,sub — no FMA
                float e0 = c.z * (py - a.y) - c.w * (px - a.x);
                float e1 = d.x * (py - a.w) - d.y * (px - a.z);
                float e2 = d.z * (py - c.y) - d.w * (px - c.x);
                float mn = fminf(fminf(e0, e1), e2);
                float mx = fmaxf(fmaxf(e0, e1), e2);
                covered = covered || (mn >= 0.0f) || (mx <= 0.0f);
            }
        }
    }

    float val = covered ? 1.0f : 0.0f;
    size_t o = ((size_t)(b * HW + py_i) * HW + px_i) * 3;
    out[o + 0] = val;
    out[o + 1] = val;
    out[o + 2] = val;
}

extern "C" void kernel_launch(void* const* d_in, const int* in_sizes, int n_in,
                              void* d_out, int out_size, void* d_ws, size_t ws_size,
                              hipStream_t stream) {
    const float* verts = (const float*)d_in[0];   // [2,4096,3] f32
    const int*   faces = (const int*)d_in[1];     // [2,4096,3] i32
    const float* R     = (const float*)d_in[2];   // [2,3,3]    f32
    const float* T     = (const float*)d_in[3];   // [2,3]      f32
    float*       out   = (float*)d_out;           // [2,256,256,3] f32

    dim3 grid(256, BATCH);
    fused_raster_kernel<<<grid, 256, 0, stream>>>(verts, faces, R, T, out);
}

// Round 6
// 63.594 us; speedup vs baseline: 1.0556x; 1.0556x over previous
//
#include <hip/hip_runtime.h>

// KaolinRenderer: coverage-mask rasterizer.
// Output = repeat(mask[B,H,W], 3) — the reference z-buffer is dead code.
//
// BIT-EXACTNESS IS CRITICAL: mask is binary, threshold 2e-2. Faces with
// w-clamped vertices (|ndc| ~1e8) have catastrophically-cancelling edge
// functions whose sign is rounding-determined. We mirror the numpy reference's
// float32 op order exactly and disable FMA contraction. Skipping faces once
// `covered` is true is safe (sticky OR); changing per-face arithmetic is not.
//
// R6 (R5 fused version regressed — per-block redundant transform put a
// dependent gather chain on every block's critical path; reverted to R4's
// two-kernel shape): face_pack writes only the 6 NDC coords per face (24B).
// Raster: each lane culls its own face fully in registers (conservative
// half-plane interval cull, R4-validated err bound), ballot-compacts, then
// survivors' coords are broadcast via __shfl from the holding lane — the
// exact-test inner loop has NO memory ops (R4 paid 3 dependent ~200-cyc
// broadcast loads per survivor). Per-lane diff recompute after shuffle is
// bit-exact: same f32 operands, same ops as the reference's broadcast.

#pragma clang fp contract(off)

#define HW      256
#define BATCH   2
#define VCOUNT  4096
#define FCOUNT  4096
#define CULL_EPS 1.52587890625e-05f   // 2^-16

__global__ __launch_bounds__(256)
void face_pack_kernel(const float* __restrict__ verts,
                      const int* __restrict__ faces,
                      const float* __restrict__ R,
                      const float* __restrict__ T,
                      float4* __restrict__ fxy4,   // [B*F] (x0,y0,x1,y1)
                      float2* __restrict__ fxy2)   // [B*F] (x2,y2)
{
#pragma clang fp contract(off)
    int gid = blockIdx.x * blockDim.x + threadIdx.x;
    if (gid >= BATCH * FCOUNT) return;
    int b = gid / FCOUNT;

    const float fproj = 1.7320508075688772f;   // 1/tan(30deg), f64->f32 like numpy

    const float* Rb = R + b * 9;
    const float* Tb = T + b * 3;

    // t_i = -((Rt[i][0]*T0 + Rt[i][1]*T1) + Rt[i][2]*T2), Rt[i][j] = R[j][i]
    float t0 = -((Rb[0*3+0]*Tb[0] + Rb[1*3+0]*Tb[1]) + Rb[2*3+0]*Tb[2]);
    float t1 = -((Rb[0*3+1]*Tb[0] + Rb[1*3+1]*Tb[1]) + Rb[2*3+1]*Tb[2]);
    float t2 = -((Rb[0*3+2]*Tb[0] + Rb[1*3+2]*Tb[1]) + Rb[2*3+2]*Tb[2]);

    // VP rows 0 (x), 1 (y), 3 (w) only.
    float VP00 = fproj * Rb[0*3+0], VP01 = fproj * Rb[1*3+0],
          VP02 = fproj * Rb[2*3+0], VP03 = fproj * t0;
    float VP10 = fproj * Rb[0*3+1], VP11 = fproj * Rb[1*3+1],
          VP12 = fproj * Rb[2*3+1], VP13 = fproj * t1;
    float VP30 = -Rb[0*3+2], VP31 = -Rb[1*3+2],
          VP32 = -Rb[2*3+2], VP33 = -t2;

    const int* fp = faces + (size_t)gid * 3;
    float xs[3], ys[3];
#pragma unroll
    for (int j = 0; j < 3; ++j) {
        const float* vv = verts + ((size_t)b * VCOUNT + fp[j]) * 3;
        float vx = vv[0], vy = vv[1], vz = vv[2];
        // Identical op sequence to the reference einsum (sequential adds),
        // contract off => bit-identical NDC for every reference to a vertex.
        float cx = ((vx*VP00 + vy*VP01) + vz*VP02) + VP03;
        float cy = ((vx*VP10 + vy*VP11) + vz*VP12) + VP13;
        float cw = ((vx*VP30 + vy*VP31) + vz*VP32) + VP33;
        float w = fmaxf(cw, 1e-8f);
        xs[j] = cx / w;
        ys[j] = cy / w;
    }

    fxy4[gid] = make_float4(xs[0], ys[0], xs[1], ys[1]);
    fxy2[gid] = make_float2(xs[2], ys[2]);
}

__global__ __launch_bounds__(256)
void raster_kernel(const float4* __restrict__ fxy4,
                   const float2* __restrict__ fxy2,
                   float* __restrict__ out)
{
#pragma clang fp contract(off)
    int b    = blockIdx.y;
    int tile = blockIdx.x;                       // 16x16 tiles over 256x256
    int tx = (tile & 15) << 4;
    int ty = (tile >> 4) << 4;
    int px_i = tx + (threadIdx.x & 15);
    int py_i = ty + (threadIdx.x >> 4);

    // Same formula as reference: ((i + 0.5)/W)*2 - 1
    float px = (((float)px_i + 0.5f) / 256.0f) * 2.0f - 1.0f;
    float py = (((float)py_i + 0.5f) / 256.0f) * 2.0f - 1.0f;

    // This wave's 16x4 strip rect (pixel formula is monotone in index).
    int wave = threadIdx.x >> 6;
    int lane = threadIdx.x & 63;
    int ry   = ty + wave * 4;
    float pxlo = (((float)tx        + 0.5f) / 256.0f) * 2.0f - 1.0f;
    float pxhi = (((float)(tx + 15) + 0.5f) / 256.0f) * 2.0f - 1.0f;
    float pylo = (((float)ry        + 0.5f) / 256.0f) * 2.0f - 1.0f;
    float pyhi = (((float)(ry + 3)  + 0.5f) / 256.0f) * 2.0f - 1.0f;

    const float4* f4 = fxy4 + (size_t)b * FCOUNT;
    const float2* f2 = fxy2 + (size_t)b * FCOUNT;

    bool covered = false;

    for (int g = 0; g < FCOUNT; g += 64) {
        if (__all((int)covered)) break;

        // Phase 1: lane owns face g+lane; coalesced 24B load, all-register cull.
        float4 q0 = f4[g + lane];
        float2 q1 = f2[g + lane];
        float x0 = q0.x, y0 = q0.y, x1 = q0.z, y1 = q0.w;
        float x2 = q1.x, y2 = q1.y;
        // Diffs: same ops as the reference's broadcast (x1-x0) etc.
        float d01x = x1 - x0, d01y = y1 - y0;
        float d12x = x2 - x1, d12y = y2 - y1;
        float d20x = x0 - x2, d20y = y0 - y2;

        // Conservative cull: e(p) ~= A*py + B*px + C over the strip rect.
        // Skippable iff some edge certifies e<0 everywhere AND some edge
        // certifies e>0 everywhere (kills both sign branches of `inside`).
        bool killneg = false, killpos = false;
        {
            float A[3]  = { d01x, d12x, d20x };
            float Bc[3] = { -d01y, -d12y, -d20y };
            float xa[3] = { x0, x1, x2 };
            float ya[3] = { y0, y1, y2 };
#pragma unroll
            for (int e = 0; e < 3; ++e) {
                float C = (-Bc[e]) * xa[e] - A[e] * ya[e];
                float err = CULL_EPS * (fabsf(A[e])  * (1.0f + fabsf(ya[e]))
                                      + fabsf(Bc[e]) * (1.0f + fabsf(xa[e])));
                float yh = (A[e]  > 0.0f) ? pyhi : pylo;
                float yl = (A[e]  > 0.0f) ? pylo : pyhi;
                float xh = (Bc[e] > 0.0f) ? pxhi : pxlo;
                float xl = (Bc[e] > 0.0f) ? pxlo : pxhi;
                float hi = A[e] * yh + Bc[e] * xh + C;
                float lo = A[e] * yl + Bc[e] * xl + C;
                killneg = killneg || (hi < -err);
                killpos = killpos || (lo >  err);
            }
        }
        bool skip = killneg && killpos;

        // Phase 2: survivors broadcast from the holding lane — no memory ops.
        unsigned long long m = __ballot((int)!skip);
        while (m) {
            if (__all((int)covered)) break;
            int k = __ffsll((long long)m) - 1;
            m &= m - 1;
            float bx0 = __shfl(x0, k), by0 = __shfl(y0, k);
            float bx1 = __shfl(x1, k), by1 = __shfl(y1, k);
            float bx2 = __shfl(x2, k), by2 = __shfl(y2, k);
            // Recomputed diffs: identical f32 operands+op as reference.
            float bd01x = bx1 - bx0, bd01y = by1 - by0;
            float bd12x = bx2 - bx1, bd12y = by2 - by1;
            float bd20x = bx0 - bx2, bd20y = by0 - by2;
            // e = (x1-x0)*(py-y0) - (y1-y0)*(px-x0): mul, mul, sub — no FMA
            float e0 = bd01x * (py - by0) - bd01y * (px - bx0);
            float e1 = bd12x * (py - by1) - bd12y * (px - bx1);
            float e2 = bd20x * (py - by2) - bd20y * (px - bx2);
            float mn = fminf(fminf(e0, e1), e2);
            float mx = fmaxf(fmaxf(e0, e1), e2);
            covered = covered || (mn >= 0.0f) || (mx <= 0.0f);
        }
    }

    float val = covered ? 1.0f : 0.0f;
    size_t o = ((size_t)(b * HW + py_i) * HW + px_i) * 3;
    out[o + 0] = val;
    out[o + 1] = val;
    out[o + 2] = val;
}

extern "C" void kernel_launch(void* const* d_in, const int* in_sizes, int n_in,
                              void* d_out, int out_size, void* d_ws, size_t ws_size,
                              hipStream_t stream) {
    const float* verts = (const float*)d_in[0];   // [2,4096,3] f32
    const int*   faces = (const int*)d_in[1];     // [2,4096,3] i32
    const float* R     = (const float*)d_in[2];   // [2,3,3]    f32
    const float* T     = (const float*)d_in[3];   // [2,3]      f32
    float*       out   = (float*)d_out;           // [2,256,256,3] f32

    float4* fxy4 = (float4*)d_ws;                        // 128 KiB
    float2* fxy2 = (float2*)(fxy4 + BATCH * FCOUNT);     // 64 KiB

    int nf = BATCH * FCOUNT;
    face_pack_kernel<<<(nf + 255) / 256, 256, 0, stream>>>(verts, faces, R, T,
                                                           fxy4, fxy2);

    dim3 grid(256, BATCH);
    raster_kernel<<<grid, 256, 0, stream>>>(fxy4, fxy2, out);
}